// Round 5
// baseline (455.877 us; speedup 1.0000x reference)
//
#include <hip/hip_runtime.h>
#include <hip/hip_cooperative_groups.h>

namespace cg = cooperative_groups;

#define NF 512
#define NH 3
#define NC 7
#define RB 512         // rows per dst bucket (power of two)
#define RBS 9          // log2(RB)
#define G1 512         // slice count == fused grid size (power of two)
#define NBMAX 256      // max buckets supported by fast path
#define FBLK 512       // fused grid blocks
#define SAGF 2         // agg slices per bucket (fused)
#define SAG 4          // agg slices per bucket (fallback)

// ---------- common ----------

__device__ __forceinline__ int load_idx(const void* base, long long i, int is32) {
    return is32 ? ((const int*)base)[i] : (int)((const long long*)base)[i];
}

// Per-block inline dtype detection: int64 layout has all-odd-words zero over the
// first 2048 pairs; int32 layout has (almost surely) nonzero there.
__device__ __forceinline__ int detect_is32(const int* __restrict__ ei, int E, int* anynz) {
    if (threadIdx.x == 0) *anynz = 0;
    __syncthreads();
    int lim = E < 2048 ? E : 2048;
    int nz = 0;
    for (int i = threadIdx.x; i < lim; i += blockDim.x) nz |= ei[2 * i + 1];
    if (nz) atomicOr(anynz, 1);
    __syncthreads();
    return *anynz;
}

// ---------- fused cooperative kernel ----------

union SMem {
    int cnt[NBMAX];                         // hist counts
    struct { int bst[NBMAX]; int cur[NBMAX]; } so;   // sort cursors
    int dcnt[RB];                           // degree histogram
    float u[RB * 3];                        // agg image
};

__global__ __launch_bounds__(256) void k_fused(
        const float* __restrict__ x, const void* __restrict__ ei,
        const float* __restrict__ Wg, const float* __restrict__ bg,
        const float* __restrict__ Wo, const float* __restrict__ bo,
        int* __restrict__ hist, int* __restrict__ bcount,
        float* __restrict__ dis, float4* __restrict__ xw4,
        unsigned* __restrict__ recs, float* __restrict__ partial,
        float* __restrict__ outH, float* __restrict__ outZ,
        int N, int E, int NBv) {
    cg::grid_group grid = cg::this_grid();
    __shared__ SMem sm;
    __shared__ int anynz;
    __shared__ int wsum[4];

    const int t = threadIdx.x;
    const int lane = t & 63;
    const int w = t >> 6;
    const int blk = blockIdx.x;
    const int is32 = detect_is32((const int*)ei, E, &anynz);

    // ---- Phase A: histogram of this block's edge slice + full GEMM (unscaled) ----
    for (int i = t; i < NBv; i += 256) sm.cnt[i] = 0;
    __syncthreads();
    const int EB = (E + FBLK - 1) / FBLK;
    const int e0 = blk * EB;
    const int e1 = min(E, e0 + EB);
    for (int i = e0 + t; i < e1; i += 256) {
        int d = load_idx(ei, (long long)E + i, is32);
        atomicAdd(&sm.cnt[d >> RBS], 1);
    }
    __syncthreads();
    for (int b = t; b < NBv; b += 256) hist[b * G1 + blk] = sm.cnt[b];

    {   // GEMM: one wave per row, W slice in registers, grid-stride
        float4 w4[6];
        const float4* wp = (const float4*)Wg;
#pragma unroll
        for (int j = 0; j < 6; ++j) w4[j] = wp[lane * 6 + j];
        const float* wf = (const float*)w4;
        const int nwaves = FBLK * 4;
        int wid = blk * 4 + w;
        for (int row = wid; row < N; row += nwaves) {
            const float4* xp = (const float4*)(x + (size_t)row * NF) + lane * 2;
            float4 a = xp[0], b4 = xp[1];
            float xv[8] = {a.x, a.y, a.z, a.w, b4.x, b4.y, b4.z, b4.w};
            float s0 = 0.f, s1 = 0.f, s2 = 0.f;
#pragma unroll
            for (int j = 0; j < 8; ++j) {
                s0 += xv[j] * wf[j * 3 + 0];
                s1 += xv[j] * wf[j * 3 + 1];
                s2 += xv[j] * wf[j * 3 + 2];
            }
#pragma unroll
            for (int off = 32; off; off >>= 1) {
                s0 += __shfl_down(s0, off);
                s1 += __shfl_down(s1, off);
                s2 += __shfl_down(s2, off);
            }
            if (lane == 0) xw4[row] = make_float4(s0, s1, s2, 0.f);
        }
    }
    grid.sync();

    // ---- Phase B: per-bucket exclusive scan of the G1 per-block counts ----
    if (blk < NBv) {
        int base = blk * G1 + t * 2;
        int v0 = hist[base], v1 = hist[base + 1];
        int s = v0 + v1;
        int incl = s;
#pragma unroll
        for (int off = 1; off < 64; off <<= 1) {
            int tt = __shfl_up(incl, off);
            if (lane >= off) incl += tt;
        }
        if (lane == 63) wsum[w] = incl;
        __syncthreads();
        int p = 0;
        for (int j = 0; j < w; ++j) p += wsum[j];
        int excl = p + incl - s;
        hist[base] = excl;
        hist[base + 1] = excl + v0;
        if (t == 255) bcount[blk] = p + incl;
    }
    grid.sync();

    // ---- Phase C+D: block-local bstart scan, then counting-sort this slice ----
    if (w == 0) {
        int v[4];
        int s = 0;
#pragma unroll
        for (int j = 0; j < 4; ++j) {
            int i = lane * 4 + j;
            v[j] = (i < NBv) ? bcount[i] : 0;
            s += v[j];
        }
        int incl = s;
#pragma unroll
        for (int off = 1; off < 64; off <<= 1) {
            int tt = __shfl_up(incl, off);
            if (lane >= off) incl += tt;
        }
        int run = incl - s;
#pragma unroll
        for (int j = 0; j < 4; ++j) {
            int i = lane * 4 + j;
            if (i < NBv) sm.so.bst[i] = run;
            run += v[j];
        }
    }
    __syncthreads();
    for (int b = t; b < NBv; b += 256)
        sm.so.cur[b] = sm.so.bst[b] + hist[b * G1 + blk];
    __syncthreads();
    for (int i = e0 + t; i < e1; i += 256) {
        int s = load_idx(ei, i, is32);
        int d = load_idx(ei, (long long)E + i, is32);
        int b = d >> RBS;
        int pos = atomicAdd(&sm.so.cur[b], 1);
        recs[pos] = ((unsigned)(d & (RB - 1)) << 17) | (unsigned)s;
    }
    grid.sync();

    // ---- Phase E: per-bucket in-degree -> dis = rsqrt(deg+1) ----
    if (blk < NBv) {
        for (int i = t; i < RB; i += 256) sm.dcnt[i] = 0;
        __syncthreads();
        // bstart recompute: cheap block-local sum not needed; bstart = prefix; use bcount scan done by wave0 earlier?
        // Recompute via global: bstart[b] was block-local; derive from recs layout: sum of bcount[0..b)
        int s0r = 0;
        // one wave computes it; broadcast through LDS
        if (t == 0) {
            int acc = 0;
            for (int j = 0; j < blk; ++j) acc += bcount[j];
            sm.dcnt[0] = acc;   // temporarily stash; safe: overwritten region re-inited? no - careful
        }
        __syncthreads();
        s0r = sm.dcnt[0];
        __syncthreads();
        if (t == 0) sm.dcnt[0] = 0;   // restore the zero for row 0 count
        __syncthreads();
        int s1r = s0r + bcount[blk];
        for (int i = s0r + t; i < s1r; i += 256)
            atomicAdd(&sm.dcnt[recs[i] >> 17], 1);
        __syncthreads();
        int rbase = blk << RBS;
        for (int r = t; r < RB; r += 256) {
            int row = rbase + r;
            if (row < N) dis[row] = rsqrtf((float)(sm.dcnt[r] + 1));
        }
    }
    grid.sync();

    // ---- Phase F: aggregation u[d] += dis[src]*xw[src] into LDS image, write partial ----
    {
        int b = blk >> 1, s = blk & 1;
        if (b < NBv) {
            for (int i = t; i < RB * 3; i += 256) sm.u[i] = 0.f;
            __syncthreads();
            // bucket start
            if (t == 0) {
                int acc = 0;
                for (int j = 0; j < b; ++j) acc += bcount[j];
                wsum[0] = acc;
            }
            __syncthreads();
            int base = wsum[0];
            long long cnt = bcount[b];
            int i0 = base + (int)(cnt * s / SAGF);
            int i1 = base + (int)(cnt * (s + 1) / SAGF);
            for (int i = i0 + t; i < i1; i += 256) {
                unsigned rec = recs[i];
                int src = rec & 0x1FFFF;
                int r = rec >> 17;
                float ds = dis[src];
                float4 v = xw4[src];
                atomicAdd(&sm.u[r * 3 + 0], ds * v.x);
                atomicAdd(&sm.u[r * 3 + 1], ds * v.y);
                atomicAdd(&sm.u[r * 3 + 2], ds * v.z);
            }
            __syncthreads();
            float4* pp = (float4*)partial + (size_t)blk * RB;
            for (int r = t; r < RB; r += 256)
                pp[r] = make_float4(sm.u[r * 3], sm.u[r * 3 + 1], sm.u[r * 3 + 2], 0.f);
        }
    }
    grid.sync();

    // ---- Phase G: final = relu(dis*(u + dis*xw) + bg); out GEMM ----
    {
        float b0 = bg[0], b1 = bg[1], b2 = bg[2];
        float wo[3][NC], boo[NC];
#pragma unroll
        for (int c = 0; c < NC; ++c) {
            wo[0][c] = Wo[c]; wo[1][c] = Wo[NC + c]; wo[2][c] = Wo[2 * NC + c];
            boo[c] = bo[c];
        }
        const float4* pp = (const float4*)partial;
        for (int i = blk * 256 + t; i < N; i += FBLK * 256) {
            int b = i >> RBS, r = i & (RB - 1);
            float4 va = pp[(size_t)(b * 2 + 0) * RB + r];
            float4 vb = pp[(size_t)(b * 2 + 1) * RB + r];
            float4 yv = xw4[i];
            float di = dis[i];
            float h0 = fmaxf(di * (va.x + vb.x + di * yv.x) + b0, 0.f);
            float h1 = fmaxf(di * (va.y + vb.y + di * yv.y) + b1, 0.f);
            float h2 = fmaxf(di * (va.z + vb.z + di * yv.z) + b2, 0.f);
            outH[i * 3 + 0] = h0; outH[i * 3 + 1] = h1; outH[i * 3 + 2] = h2;
#pragma unroll
            for (int c = 0; c < NC; ++c)
                outZ[i * NC + c] = h0 * wo[0][c] + h1 * wo[1][c] + h2 * wo[2][c] + boo[c];
        }
    }
}

// ---------- non-cooperative fast pipeline (R4 fallback) ----------

__global__ __launch_bounds__(256) void k_hist(const void* __restrict__ ei,
                                              int* __restrict__ hist, int E, int NBv) {
    __shared__ int cnt[NBMAX];
    __shared__ int anynz;
    int is32 = detect_is32((const int*)ei, E, &anynz);
    for (int i = threadIdx.x; i < NBv; i += 256) cnt[i] = 0;
    __syncthreads();
    int EB = (E + G1 - 1) / G1;
    int e0 = blockIdx.x * EB;
    int e1 = min(E, e0 + EB);
    for (int i = e0 + threadIdx.x; i < e1; i += 256) {
        int d = load_idx(ei, (long long)E + i, is32);
        atomicAdd(&cnt[d >> RBS], 1);
    }
    __syncthreads();
    for (int b = threadIdx.x; b < NBv; b += 256)
        hist[b * G1 + blockIdx.x] = cnt[b];
}

__global__ __launch_bounds__(512) void k_scanb(int* __restrict__ hist, int* __restrict__ bcount) {
    __shared__ int wsum[8];
    int b = blockIdx.x;
    int t = threadIdx.x, lane = t & 63, w = t >> 6;
    int v = hist[b * G1 + t];
    int incl = v;
#pragma unroll
    for (int off = 1; off < 64; off <<= 1) {
        int tt = __shfl_up(incl, off);
        if (lane >= off) incl += tt;
    }
    if (lane == 63) wsum[w] = incl;
    __syncthreads();
    int p = 0;
    for (int j = 0; j < w; ++j) p += wsum[j];
    hist[b * G1 + t] = p + incl - v;
    if (t == 511) bcount[b] = p + incl;
}

__global__ __launch_bounds__(64) void k_scano(const int* __restrict__ bcount,
                                              int* __restrict__ bstart, int NBv) {
    int lane = threadIdx.x;
    int v[4];
    int s = 0;
#pragma unroll
    for (int j = 0; j < 4; ++j) {
        int i = lane * 4 + j;
        v[j] = (i < NBv) ? bcount[i] : 0;
        s += v[j];
    }
    int incl = s;
#pragma unroll
    for (int off = 1; off < 64; off <<= 1) {
        int t = __shfl_up(incl, off);
        if (lane >= off) incl += t;
    }
    int run = incl - s;
#pragma unroll
    for (int j = 0; j < 4; ++j) {
        int i = lane * 4 + j;
        if (i < NBv) bstart[i] = run;
        run += v[j];
    }
}

__global__ __launch_bounds__(256) void k_sort(const void* __restrict__ ei,
                                              const int* __restrict__ hist,
                                              const int* __restrict__ bstart,
                                              unsigned* __restrict__ recs, int E, int NBv) {
    __shared__ int cur[NBMAX];
    __shared__ int anynz;
    int is32 = detect_is32((const int*)ei, E, &anynz);
    for (int b = threadIdx.x; b < NBv; b += 256)
        cur[b] = bstart[b] + hist[b * G1 + blockIdx.x];
    __syncthreads();
    int EB = (E + G1 - 1) / G1;
    int e0 = blockIdx.x * EB;
    int e1 = min(E, e0 + EB);
    for (int i = e0 + threadIdx.x; i < e1; i += 256) {
        int s = load_idx(ei, i, is32);
        int d = load_idx(ei, (long long)E + i, is32);
        int b = d >> RBS;
        int pos = atomicAdd(&cur[b], 1);
        recs[pos] = ((unsigned)(d & (RB - 1)) << 17) | (unsigned)s;
    }
}

__global__ __launch_bounds__(256) void k_deg(const unsigned* __restrict__ recs,
                                             const int* __restrict__ bstart, const int* __restrict__ bcount,
                                             float* __restrict__ dis, int n) {
    __shared__ int cnt[RB];
    for (int i = threadIdx.x; i < RB; i += 256) cnt[i] = 0;
    __syncthreads();
    int b = blockIdx.x;
    int s0 = bstart[b], s1 = s0 + bcount[b];
    for (int i = s0 + threadIdx.x; i < s1; i += 256)
        atomicAdd(&cnt[recs[i] >> 17], 1);
    __syncthreads();
    int rbase = b << RBS;
    for (int r = threadIdx.x; r < RB; r += 256) {
        int row = rbase + r;
        if (row < n) dis[row] = rsqrtf((float)(cnt[r] + 1));
    }
}

__global__ __launch_bounds__(256) void k_gemm(const float* __restrict__ x, const float* __restrict__ W,
                                              const float* __restrict__ dis, float4* __restrict__ y4,
                                              int n, int nwaves) {
    int lane = threadIdx.x & 63;
    float4 w4[6];
    const float4* wp = (const float4*)W;
#pragma unroll
    for (int j = 0; j < 6; ++j) w4[j] = wp[lane * 6 + j];
    const float* wf = (const float*)w4;

    int wid = blockIdx.x * 4 + (threadIdx.x >> 6);
    for (int row = wid; row < n; row += nwaves) {
        const float4* xp = (const float4*)(x + (size_t)row * NF) + lane * 2;
        float4 a = xp[0], b = xp[1];
        float xv[8] = {a.x, a.y, a.z, a.w, b.x, b.y, b.z, b.w};
        float s0 = 0.f, s1 = 0.f, s2 = 0.f;
#pragma unroll
        for (int j = 0; j < 8; ++j) {
            s0 += xv[j] * wf[j * 3 + 0];
            s1 += xv[j] * wf[j * 3 + 1];
            s2 += xv[j] * wf[j * 3 + 2];
        }
#pragma unroll
        for (int off = 32; off; off >>= 1) {
            s0 += __shfl_down(s0, off);
            s1 += __shfl_down(s1, off);
            s2 += __shfl_down(s2, off);
        }
        if (lane == 0) {
            float di = dis[row];
            y4[row] = make_float4(s0 * di, s1 * di, s2 * di, 0.f);
        }
    }
}

__global__ __launch_bounds__(256) void k_agg(const unsigned* __restrict__ recs,
                                             const int* __restrict__ bstart, const int* __restrict__ bcount,
                                             const float4* __restrict__ y4, float* __restrict__ partial) {
    __shared__ float u[RB * 3];
    for (int i = threadIdx.x; i < RB * 3; i += 256) u[i] = 0.f;
    __syncthreads();
    int b = blockIdx.x / SAG, s = blockIdx.x % SAG;
    int base = bstart[b];
    long long cnt = bcount[b];
    int i0 = base + (int)(cnt * s / SAG);
    int i1 = base + (int)(cnt * (s + 1) / SAG);
    for (int i = i0 + threadIdx.x; i < i1; i += 256) {
        unsigned rec = recs[i];
        int src = rec & 0x1FFFF;
        int r = rec >> 17;
        float4 v = y4[src];
        atomicAdd(&u[r * 3 + 0], v.x);
        atomicAdd(&u[r * 3 + 1], v.y);
        atomicAdd(&u[r * 3 + 2], v.z);
    }
    __syncthreads();
    float4* pp = (float4*)partial + (size_t)blockIdx.x * RB;
    for (int r = threadIdx.x; r < RB; r += 256)
        pp[r] = make_float4(u[r * 3], u[r * 3 + 1], u[r * 3 + 2], 0.f);
}

__global__ __launch_bounds__(256) void k_final(const float* __restrict__ partial, const float4* __restrict__ y4,
                                               const float* __restrict__ dis, const float* __restrict__ bg,
                                               const float* __restrict__ Wo, const float* __restrict__ bo,
                                               float* __restrict__ outH, float* __restrict__ outZ, int n) {
    int i = blockIdx.x * 256 + threadIdx.x;
    if (i >= n) return;
    int b = i >> RBS, r = i & (RB - 1);
    const float4* pp = (const float4*)partial;
    float u0 = 0.f, u1 = 0.f, u2 = 0.f;
#pragma unroll
    for (int s = 0; s < SAG; ++s) {
        float4 v = pp[(size_t)(b * SAG + s) * RB + r];
        u0 += v.x; u1 += v.y; u2 += v.z;
    }
    float4 yv = y4[i];
    float di = dis[i];
    float h0 = fmaxf(di * (u0 + yv.x) + bg[0], 0.f);
    float h1 = fmaxf(di * (u1 + yv.y) + bg[1], 0.f);
    float h2 = fmaxf(di * (u2 + yv.z) + bg[2], 0.f);
    outH[i * 3 + 0] = h0; outH[i * 3 + 1] = h1; outH[i * 3 + 2] = h2;
#pragma unroll
    for (int c = 0; c < NC; ++c)
        outZ[i * NC + c] = h0 * Wo[c] + h1 * Wo[NC + c] + h2 * Wo[2 * NC + c] + bo[c];
}

// ---------- atomic fallback (round-1 structure) ----------

__global__ void k_detect_fb(const int* ei, int* flag, int E) {
    __shared__ int anynz;
    if (threadIdx.x == 0) anynz = 0;
    __syncthreads();
    int lim = E < 2048 ? E : 2048;
    int nz = 0;
    for (int i = threadIdx.x; i < lim; i += blockDim.x) nz |= ei[2 * i + 1];
    if (nz) atomicOr(&anynz, 1);
    __syncthreads();
    if (threadIdx.x == 0) *flag = anynz;
}
__global__ void k_init_fb(float* deg, int n) {
    int i = blockIdx.x * blockDim.x + threadIdx.x;
    if (i < n) deg[i] = 1.0f;
}
__global__ void k_degc_fb(const void* ei, const int* flag, float* deg, int E, int n) {
    int i = blockIdx.x * blockDim.x + threadIdx.x;
    if (i >= E) return;
    int d = load_idx(ei, (long long)E + i, *flag);
    if ((unsigned)d < (unsigned)n) atomicAdd(&deg[d], 1.0f);
}
__global__ __launch_bounds__(256) void k_gemm_fb(const float* x, const float* W, float* degdis,
                                                 float* xw, float* agg, int n) {
    __shared__ float wl[NF * NH];
    for (int j = threadIdx.x; j < NF * NH; j += 256) wl[j] = W[j];
    __syncthreads();
    int row = blockIdx.x * 4 + (threadIdx.x >> 6);
    if (row >= n) return;
    int lane = threadIdx.x & 63;
    const float4* xp = (const float4*)(x + (size_t)row * NF + lane * 8);
    float4 a = xp[0], b = xp[1];
    float xv[8] = {a.x, a.y, a.z, a.w, b.x, b.y, b.z, b.w};
    float s0 = 0.f, s1 = 0.f, s2 = 0.f;
    int f0 = lane * 8;
#pragma unroll
    for (int j = 0; j < 8; ++j) {
        float v = xv[j];
        const float* wp = &wl[(f0 + j) * NH];
        s0 += v * wp[0]; s1 += v * wp[1]; s2 += v * wp[2];
    }
#pragma unroll
    for (int off = 32; off; off >>= 1) {
        s0 += __shfl_down(s0, off); s1 += __shfl_down(s1, off); s2 += __shfl_down(s2, off);
    }
    if (lane == 0) {
        float d = degdis[row];
        float di = d > 0.f ? rsqrtf(d) : 0.f;
        degdis[row] = di;
        xw[row * 3 + 0] = s0; xw[row * 3 + 1] = s1; xw[row * 3 + 2] = s2;
        float n2 = di * di;
        agg[row * 3 + 0] = s0 * n2; agg[row * 3 + 1] = s1 * n2; agg[row * 3 + 2] = s2 * n2;
    }
}
__global__ void k_scat_fb(const void* ei, const int* flag, const float* dis, const float* xw,
                          float* agg, int E, int n) {
    int i = blockIdx.x * blockDim.x + threadIdx.x;
    if (i >= E) return;
    int is32 = *flag;
    int s = load_idx(ei, i, is32);
    int d = load_idx(ei, (long long)E + i, is32);
    if ((unsigned)s >= (unsigned)n || (unsigned)d >= (unsigned)n) return;
    float w = dis[s] * dis[d];
    atomicAdd(&agg[d * 3 + 0], xw[s * 3 + 0] * w);
    atomicAdd(&agg[d * 3 + 1], xw[s * 3 + 1] * w);
    atomicAdd(&agg[d * 3 + 2], xw[s * 3 + 2] * w);
}
__global__ void k_final_fb(const float* agg, const float* bg, const float* Wo, const float* bo,
                           float* outH, float* outZ, int n) {
    int i = blockIdx.x * blockDim.x + threadIdx.x;
    if (i >= n) return;
    float h0 = fmaxf(agg[i * 3 + 0] + bg[0], 0.f);
    float h1 = fmaxf(agg[i * 3 + 1] + bg[1], 0.f);
    float h2 = fmaxf(agg[i * 3 + 2] + bg[2], 0.f);
    outH[i * 3 + 0] = h0; outH[i * 3 + 1] = h1; outH[i * 3 + 2] = h2;
#pragma unroll
    for (int c = 0; c < NC; ++c)
        outZ[i * NC + c] = h0 * Wo[c] + h1 * Wo[NC + c] + h2 * Wo[2 * NC + c] + bo[c];
}

// ---------- launch ----------

extern "C" void kernel_launch(void* const* d_in, const int* in_sizes, int n_in,
                              void* d_out, int out_size, void* d_ws, size_t ws_size,
                              hipStream_t stream) {
    const float* x  = (const float*)d_in[0];
    const void*  ei = d_in[1];
    const float* Wg = (const float*)d_in[2];
    const float* bg = (const float*)d_in[3];
    const float* Wo = (const float*)d_in[4];
    const float* bo = (const float*)d_in[5];

    const int N = in_sizes[0] / NF;
    const int E = in_sizes[1] / 2;
    const int NBv = (N + RB - 1) >> RBS;

    float* outH = (float*)d_out;
    float* outZ = outH + (size_t)3 * N;

    int*   wsI = (int*)d_ws;
    float* wsF = (float*)d_ws;

    size_t off = 64;
    int* hist   = wsI + off; off += (size_t)NBMAX * G1;
    int* bstart = wsI + off; off += NBMAX;
    int* bcount = wsI + off; off += NBMAX;
    float* dis  = wsF + off; off += N;
    off = (off + 3) & ~(size_t)3;
    float* y4   = wsF + off; off += (size_t)4 * N;
    unsigned* recs = (unsigned*)(wsI + off); off += E;
    off = (off + 3) & ~(size_t)3;
    float* partial = wsF + off; off += (size_t)NBv * SAG * RB * 4;   // max of fused(2)/fallback(4)

    bool fast = (off * 4 <= ws_size) && (N <= 131072) && (NBv <= NBMAX);

    dim3 blk(256);
    if (fast) {
        // try fused cooperative path
        bool coop_ok = false;
        int dev = 0;
        if (hipGetDevice(&dev) == hipSuccess) {
            hipDeviceProp_t prop;
            if (hipGetDeviceProperties(&prop, dev) == hipSuccess && prop.cooperativeLaunch) {
                int occ = 0;
                if (hipOccupancyMaxActiveBlocksPerMultiprocessor(&occ, k_fused, 256, 0) == hipSuccess &&
                    (long long)occ * prop.multiProcessorCount >= FBLK) {
                    int nN = N, nE = E, nNBv = NBv;
                    void* args[] = {
                        (void*)&x, (void*)&ei, (void*)&Wg, (void*)&bg, (void*)&Wo, (void*)&bo,
                        (void*)&hist, (void*)&bcount, (void*)&dis, (void*)&y4, (void*)&recs,
                        (void*)&partial, (void*)&outH, (void*)&outZ,
                        (void*)&nN, (void*)&nE, (void*)&nNBv };
                    if (hipLaunchCooperativeKernel((const void*)k_fused, dim3(FBLK), dim3(256),
                                                   args, 0, stream) == hipSuccess)
                        coop_ok = true;
                }
            }
        }
        if (!coop_ok) {
            k_hist<<<G1, blk, 0, stream>>>(ei, hist, E, NBv);
            k_scanb<<<NBv, dim3(512), 0, stream>>>(hist, bcount);
            k_scano<<<1, dim3(64), 0, stream>>>(bcount, bstart, NBv);
            k_sort<<<G1, blk, 0, stream>>>(ei, hist, bstart, recs, E, NBv);
            k_deg<<<NBv, blk, 0, stream>>>(recs, bstart, bcount, dis, N);
            k_gemm<<<2048, blk, 0, stream>>>(x, Wg, dis, (float4*)y4, N, 2048 * 4);
            k_agg<<<NBv * SAG, blk, 0, stream>>>(recs, bstart, bcount, (const float4*)y4, partial);
            k_final<<<(N + 255) / 256, blk, 0, stream>>>(partial, (const float4*)y4, dis, bg, Wo, bo, outH, outZ, N);
        }
    } else {
        int* flag  = wsI;
        float* deg = wsF + 64;
        float* xw  = deg + N;
        float* agg = xw + (size_t)3 * N;
        int gN = (N + 255) / 256, gE = (E + 255) / 256;
        k_detect_fb<<<1, blk, 0, stream>>>((const int*)ei, flag, E);
        k_init_fb<<<gN, blk, 0, stream>>>(deg, N);
        k_degc_fb<<<gE, blk, 0, stream>>>(ei, flag, deg, E, N);
        k_gemm_fb<<<(N + 3) / 4, blk, 0, stream>>>(x, Wg, deg, xw, agg, N);
        k_scat_fb<<<gE, blk, 0, stream>>>(ei, flag, deg, xw, agg, E, N);
        k_final_fb<<<gN, blk, 0, stream>>>(agg, bg, Wo, bo, outH, outZ, N);
    }
}

// Round 6
// 171.034 us; speedup vs baseline: 2.6654x; 2.6654x over previous
//
#include <hip/hip_runtime.h>

#define NF 512
#define NH 3
#define NC 7
#define RB 128         // rows per dst bucket (power of two)
#define RBS 7          // log2(RB)
#define G1 512         // histogram / sort slice blocks
#define NBMAX 1024     // max buckets (N <= 131072)
#define SAG 4          // fallback agg slices per bucket (unused in fast path)

// ---------- common ----------

__device__ __forceinline__ int load_idx(const void* base, long long i, int is32) {
    return is32 ? ((const int*)base)[i] : (int)((const long long*)base)[i];
}

// Per-block inline dtype detection: int64 layout has all-odd-words zero over the
// first 2048 pairs; int32 layout has (almost surely) nonzero there.
__device__ __forceinline__ int detect_is32(const int* __restrict__ ei, int E, int* anynz) {
    if (threadIdx.x == 0) *anynz = 0;
    __syncthreads();
    int lim = E < 2048 ? E : 2048;
    int nz = 0;
    for (int i = threadIdx.x; i < lim; i += blockDim.x) nz |= ei[2 * i + 1];
    if (nz) atomicOr(anynz, 1);
    __syncthreads();
    return *anynz;
}

// ---------- fast path ----------

__global__ __launch_bounds__(256) void k_hist(const void* __restrict__ ei,
                                              int* __restrict__ hist, int E, int NBv) {
    __shared__ int cnt[NBMAX];
    __shared__ int anynz;
    int is32 = detect_is32((const int*)ei, E, &anynz);
    for (int i = threadIdx.x; i < NBv; i += 256) cnt[i] = 0;
    __syncthreads();
    int EB = (E + G1 - 1) / G1;
    int e0 = blockIdx.x * EB;
    int e1 = min(E, e0 + EB);
    for (int i = e0 + threadIdx.x; i < e1; i += 256) {
        int d = load_idx(ei, (long long)E + i, is32);
        atomicAdd(&cnt[d >> RBS], 1);
    }
    __syncthreads();
    for (int b = threadIdx.x; b < NBv; b += 256)
        hist[b * G1 + blockIdx.x] = cnt[b];
}

// Per-bucket exclusive scan of the G1 per-block counts; emits bucket total.
__global__ __launch_bounds__(512) void k_scanb(int* __restrict__ hist, int* __restrict__ bcount) {
    __shared__ int wsum[8];
    int b = blockIdx.x;
    int t = threadIdx.x, lane = t & 63, w = t >> 6;
    int v = hist[b * G1 + t];
    int incl = v;
#pragma unroll
    for (int off = 1; off < 64; off <<= 1) {
        int tt = __shfl_up(incl, off);
        if (lane >= off) incl += tt;
    }
    if (lane == 63) wsum[w] = incl;
    __syncthreads();
    int p = 0;
    for (int j = 0; j < w; ++j) p += wsum[j];
    hist[b * G1 + t] = p + incl - v;     // bucket-local exclusive
    if (t == 511) bcount[b] = p + incl;  // bucket total
}

// Exclusive scan of up to NBMAX bucket totals -> bucket starts (one block).
__global__ __launch_bounds__(1024) void k_scano(const int* __restrict__ bcount,
                                                int* __restrict__ bstart, int NBv) {
    __shared__ int wsum[16];
    int t = threadIdx.x, lane = t & 63, w = t >> 6;
    int v = (t < NBv) ? bcount[t] : 0;
    int incl = v;
#pragma unroll
    for (int off = 1; off < 64; off <<= 1) {
        int tt = __shfl_up(incl, off);
        if (lane >= off) incl += tt;
    }
    if (lane == 63) wsum[w] = incl;
    __syncthreads();
    int p = 0;
    for (int j = 0; j < w; ++j) p += wsum[j];
    if (t < NBv) bstart[t] = p + incl - v;
}

__global__ __launch_bounds__(256) void k_sort(const void* __restrict__ ei,
                                              const int* __restrict__ hist,
                                              const int* __restrict__ bstart,
                                              unsigned* __restrict__ recs, int E, int NBv) {
    __shared__ int cur[NBMAX];
    __shared__ int anynz;
    int is32 = detect_is32((const int*)ei, E, &anynz);
    for (int b = threadIdx.x; b < NBv; b += 256)
        cur[b] = bstart[b] + hist[b * G1 + blockIdx.x];
    __syncthreads();
    int EB = (E + G1 - 1) / G1;
    int e0 = blockIdx.x * EB;
    int e1 = min(E, e0 + EB);
    for (int i = e0 + threadIdx.x; i < e1; i += 256) {
        int s = load_idx(ei, i, is32);
        int d = load_idx(ei, (long long)E + i, is32);
        int b = d >> RBS;
        int pos = atomicAdd(&cur[b], 1);      // LDS cursor only
        recs[pos] = ((unsigned)(d & (RB - 1)) << 17) | (unsigned)s;
    }
}

// Per-bucket in-degree via LDS histogram -> dis = rsqrt(deg+1)
__global__ __launch_bounds__(256) void k_deg(const unsigned* __restrict__ recs,
                                             const int* __restrict__ bstart, const int* __restrict__ bcount,
                                             float* __restrict__ dis, int n) {
    __shared__ int cnt[RB];
    for (int i = threadIdx.x; i < RB; i += 256) cnt[i] = 0;
    __syncthreads();
    int b = blockIdx.x;
    int s0 = bstart[b], s1 = s0 + bcount[b];
    for (int i = s0 + threadIdx.x; i < s1; i += 256)
        atomicAdd(&cnt[recs[i] >> 17], 1);
    __syncthreads();
    int rbase = b << RBS;
    for (int r = threadIdx.x; r < RB; r += 256) {
        int row = rbase + r;
        if (row < n) dis[row] = rsqrtf((float)(cnt[r] + 1));
    }
}

// Grid-stride, one wave per row, W slice in registers: y = dis[row]*(x@W)
__global__ __launch_bounds__(256) void k_gemm(const float* __restrict__ x, const float* __restrict__ W,
                                              const float* __restrict__ dis, float4* __restrict__ y4,
                                              int n, int nwaves) {
    int lane = threadIdx.x & 63;
    float4 w4[6];
    const float4* wp = (const float4*)W;
#pragma unroll
    for (int j = 0; j < 6; ++j) w4[j] = wp[lane * 6 + j];
    const float* wf = (const float*)w4;

    int wid = blockIdx.x * 4 + (threadIdx.x >> 6);
    for (int row = wid; row < n; row += nwaves) {
        const float4* xp = (const float4*)(x + (size_t)row * NF) + lane * 2;
        float4 a = xp[0], b = xp[1];
        float xv[8] = {a.x, a.y, a.z, a.w, b.x, b.y, b.z, b.w};
        float s0 = 0.f, s1 = 0.f, s2 = 0.f;
#pragma unroll
        for (int j = 0; j < 8; ++j) {
            s0 += xv[j] * wf[j * 3 + 0];
            s1 += xv[j] * wf[j * 3 + 1];
            s2 += xv[j] * wf[j * 3 + 2];
        }
#pragma unroll
        for (int off = 32; off; off >>= 1) {
            s0 += __shfl_down(s0, off);
            s1 += __shfl_down(s1, off);
            s2 += __shfl_down(s2, off);
        }
        if (lane == 0) {
            float di = dis[row];
            y4[row] = make_float4(s0 * di, s1 * di, s2 * di, 0.f);
        }
    }
}

// One block per bucket: aggregate u[d] = sum y[src] in LDS, then finalize
// h = relu(dis*(u + y_self) + bg), z = h@Wo + bo. No partial buffer, no extra kernel.
__global__ __launch_bounds__(256) void k_aggfinal(const unsigned* __restrict__ recs,
                                                  const int* __restrict__ bstart, const int* __restrict__ bcount,
                                                  const float4* __restrict__ y4, const float* __restrict__ dis,
                                                  const float* __restrict__ bg,
                                                  const float* __restrict__ Wo, const float* __restrict__ bo,
                                                  float* __restrict__ outH, float* __restrict__ outZ, int n) {
    __shared__ float u[RB * 3];
    for (int i = threadIdx.x; i < RB * 3; i += 256) u[i] = 0.f;
    __syncthreads();
    int b = blockIdx.x;
    int i0 = bstart[b], i1 = i0 + bcount[b];
    for (int i = i0 + threadIdx.x; i < i1; i += 256) {
        unsigned rec = recs[i];
        int src = rec & 0x1FFFF;
        int r = rec >> 17;
        float4 v = y4[src];
        atomicAdd(&u[r * 3 + 0], v.x);
        atomicAdd(&u[r * 3 + 1], v.y);
        atomicAdd(&u[r * 3 + 2], v.z);
    }
    __syncthreads();
    float b0 = bg[0], b1 = bg[1], b2 = bg[2];
    int rbase = b << RBS;
    for (int r = threadIdx.x; r < RB; r += 256) {
        int row = rbase + r;
        if (row >= n) break;
        float4 yv = y4[row];
        float di = dis[row];
        float h0 = fmaxf(di * (u[r * 3 + 0] + yv.x) + b0, 0.f);
        float h1 = fmaxf(di * (u[r * 3 + 1] + yv.y) + b1, 0.f);
        float h2 = fmaxf(di * (u[r * 3 + 2] + yv.z) + b2, 0.f);
        outH[row * 3 + 0] = h0; outH[row * 3 + 1] = h1; outH[row * 3 + 2] = h2;
#pragma unroll
        for (int c = 0; c < NC; ++c)
            outZ[row * NC + c] = h0 * Wo[c] + h1 * Wo[NC + c] + h2 * Wo[2 * NC + c] + bo[c];
    }
}

// ---------- atomic fallback (round-1 structure) ----------

__global__ void k_detect_fb(const int* ei, int* flag, int E) {
    __shared__ int anynz;
    if (threadIdx.x == 0) anynz = 0;
    __syncthreads();
    int lim = E < 2048 ? E : 2048;
    int nz = 0;
    for (int i = threadIdx.x; i < lim; i += blockDim.x) nz |= ei[2 * i + 1];
    if (nz) atomicOr(&anynz, 1);
    __syncthreads();
    if (threadIdx.x == 0) *flag = anynz;
}
__global__ void k_init_fb(float* deg, int n) {
    int i = blockIdx.x * blockDim.x + threadIdx.x;
    if (i < n) deg[i] = 1.0f;
}
__global__ void k_degc_fb(const void* ei, const int* flag, float* deg, int E, int n) {
    int i = blockIdx.x * blockDim.x + threadIdx.x;
    if (i >= E) return;
    int d = load_idx(ei, (long long)E + i, *flag);
    if ((unsigned)d < (unsigned)n) atomicAdd(&deg[d], 1.0f);
}
__global__ __launch_bounds__(256) void k_gemm_fb(const float* x, const float* W, float* degdis,
                                                 float* xw, float* agg, int n) {
    __shared__ float wl[NF * NH];
    for (int j = threadIdx.x; j < NF * NH; j += 256) wl[j] = W[j];
    __syncthreads();
    int row = blockIdx.x * 4 + (threadIdx.x >> 6);
    if (row >= n) return;
    int lane = threadIdx.x & 63;
    const float4* xp = (const float4*)(x + (size_t)row * NF + lane * 8);
    float4 a = xp[0], b = xp[1];
    float xv[8] = {a.x, a.y, a.z, a.w, b.x, b.y, b.z, b.w};
    float s0 = 0.f, s1 = 0.f, s2 = 0.f;
    int f0 = lane * 8;
#pragma unroll
    for (int j = 0; j < 8; ++j) {
        float v = xv[j];
        const float* wp = &wl[(f0 + j) * NH];
        s0 += v * wp[0]; s1 += v * wp[1]; s2 += v * wp[2];
    }
#pragma unroll
    for (int off = 32; off; off >>= 1) {
        s0 += __shfl_down(s0, off); s1 += __shfl_down(s1, off); s2 += __shfl_down(s2, off);
    }
    if (lane == 0) {
        float d = degdis[row];
        float di = d > 0.f ? rsqrtf(d) : 0.f;
        degdis[row] = di;
        xw[row * 3 + 0] = s0; xw[row * 3 + 1] = s1; xw[row * 3 + 2] = s2;
        float n2 = di * di;
        agg[row * 3 + 0] = s0 * n2; agg[row * 3 + 1] = s1 * n2; agg[row * 3 + 2] = s2 * n2;
    }
}
__global__ void k_scat_fb(const void* ei, const int* flag, const float* dis, const float* xw,
                          float* agg, int E, int n) {
    int i = blockIdx.x * blockDim.x + threadIdx.x;
    if (i >= E) return;
    int is32 = *flag;
    int s = load_idx(ei, i, is32);
    int d = load_idx(ei, (long long)E + i, is32);
    if ((unsigned)s >= (unsigned)n || (unsigned)d >= (unsigned)n) return;
    float w = dis[s] * dis[d];
    atomicAdd(&agg[d * 3 + 0], xw[s * 3 + 0] * w);
    atomicAdd(&agg[d * 3 + 1], xw[s * 3 + 1] * w);
    atomicAdd(&agg[d * 3 + 2], xw[s * 3 + 2] * w);
}
__global__ void k_final_fb(const float* agg, const float* bg, const float* Wo, const float* bo,
                           float* outH, float* outZ, int n) {
    int i = blockIdx.x * blockDim.x + threadIdx.x;
    if (i >= n) return;
    float h0 = fmaxf(agg[i * 3 + 0] + bg[0], 0.f);
    float h1 = fmaxf(agg[i * 3 + 1] + bg[1], 0.f);
    float h2 = fmaxf(agg[i * 3 + 2] + bg[2], 0.f);
    outH[i * 3 + 0] = h0; outH[i * 3 + 1] = h1; outH[i * 3 + 2] = h2;
#pragma unroll
    for (int c = 0; c < NC; ++c)
        outZ[i * NC + c] = h0 * Wo[c] + h1 * Wo[NC + c] + h2 * Wo[2 * NC + c] + bo[c];
}

// ---------- launch ----------

extern "C" void kernel_launch(void* const* d_in, const int* in_sizes, int n_in,
                              void* d_out, int out_size, void* d_ws, size_t ws_size,
                              hipStream_t stream) {
    const float* x  = (const float*)d_in[0];
    const void*  ei = d_in[1];
    const float* Wg = (const float*)d_in[2];
    const float* bg = (const float*)d_in[3];
    const float* Wo = (const float*)d_in[4];
    const float* bo = (const float*)d_in[5];

    const int N = in_sizes[0] / NF;
    const int E = in_sizes[1] / 2;
    const int NBv = (N + RB - 1) >> RBS;

    float* outH = (float*)d_out;
    float* outZ = outH + (size_t)3 * N;

    int*   wsI = (int*)d_ws;
    float* wsF = (float*)d_ws;

    size_t off = 64;
    int* hist   = wsI + off; off += (size_t)NBMAX * G1;
    int* bstart = wsI + off; off += NBMAX;
    int* bcount = wsI + off; off += NBMAX;
    float* dis  = wsF + off; off += N;
    off = (off + 3) & ~(size_t)3;
    float* y4   = wsF + off; off += (size_t)4 * N;
    unsigned* recs = (unsigned*)(wsI + off); off += E;

    bool fast = (off * 4 <= ws_size) && (N <= 131072) && (NBv <= NBMAX);

    dim3 blk(256);
    if (fast) {
        k_hist<<<G1, blk, 0, stream>>>(ei, hist, E, NBv);
        k_scanb<<<NBv, dim3(512), 0, stream>>>(hist, bcount);
        k_scano<<<1, dim3(1024), 0, stream>>>(bcount, bstart, NBv);
        k_sort<<<G1, blk, 0, stream>>>(ei, hist, bstart, recs, E, NBv);
        k_deg<<<NBv, blk, 0, stream>>>(recs, bstart, bcount, dis, N);
        k_gemm<<<2048, blk, 0, stream>>>(x, Wg, dis, (float4*)y4, N, 2048 * 4);
        k_aggfinal<<<NBv, blk, 0, stream>>>(recs, bstart, bcount, (const float4*)y4, dis,
                                            bg, Wo, bo, outH, outZ, N);
    } else {
        int* flag  = wsI;
        float* deg = wsF + 64;
        float* xw  = deg + N;
        float* agg = xw + (size_t)3 * N;
        int gN = (N + 255) / 256, gE = (E + 255) / 256;
        k_detect_fb<<<1, blk, 0, stream>>>((const int*)ei, flag, E);
        k_init_fb<<<gN, blk, 0, stream>>>(deg, N);
        k_degc_fb<<<gE, blk, 0, stream>>>(ei, flag, deg, E, N);
        k_gemm_fb<<<(N + 3) / 4, blk, 0, stream>>>(x, Wg, deg, xw, agg, N);
        k_scat_fb<<<gE, blk, 0, stream>>>(ei, flag, deg, xw, agg, E, N);
        k_final_fb<<<gN, blk, 0, stream>>>(agg, bg, Wo, bo, outH, outZ, N);
    }
}

// Round 7
// 166.691 us; speedup vs baseline: 2.7349x; 1.0261x over previous
//
#include <hip/hip_runtime.h>

#define NF 512
#define NH 3
#define NC 7
#define RB 128         // rows per dst bucket (power of two)
#define RBS 7          // log2(RB)
#define G1 256         // edge slice blocks for hist/sort
#define NBMAX 1024     // max buckets (N <= 131072)

// ---------- common ----------

__device__ __forceinline__ int load_idx(const void* base, long long i, int is32) {
    return is32 ? ((const int*)base)[i] : (int)((const long long*)base)[i];
}

// Per-block inline dtype detection: int64 layout has all-odd-words zero over the
// first 2048 pairs; int32 layout has (almost surely) nonzero there.
__device__ __forceinline__ int detect_is32(const int* __restrict__ ei, int E, int* anynz) {
    if (threadIdx.x == 0) *anynz = 0;
    __syncthreads();
    int lim = E < 2048 ? E : 2048;
    int nz = 0;
    for (int i = threadIdx.x; i < lim; i += blockDim.x) nz |= ei[2 * i + 1];
    if (nz) atomicOr(anynz, 1);
    __syncthreads();
    return *anynz;
}

// ---------- fast path ----------

__global__ __launch_bounds__(512) void k_hist(const void* __restrict__ ei,
                                              int* __restrict__ hist, int E, int NBv) {
    __shared__ int cnt[NBMAX];
    __shared__ int anynz;
    int is32 = detect_is32((const int*)ei, E, &anynz);
    for (int i = threadIdx.x; i < NBv; i += 512) cnt[i] = 0;
    __syncthreads();
    int EB = (E + G1 - 1) / G1;
    int e0 = blockIdx.x * EB;
    int e1 = min(E, e0 + EB);
    for (int i = e0 + threadIdx.x; i < e1; i += 512) {
        int d = load_idx(ei, (long long)E + i, is32);
        atomicAdd(&cnt[d >> RBS], 1);
    }
    __syncthreads();
    for (int b = threadIdx.x; b < NBv; b += 512)
        hist[b * G1 + blockIdx.x] = cnt[b];
}

// Per-bucket exclusive scan of the G1 per-block counts; emits bucket total.
__global__ __launch_bounds__(G1) void k_scanb(int* __restrict__ hist, int* __restrict__ bcount) {
    __shared__ int wsum[G1 / 64];
    int b = blockIdx.x;
    int t = threadIdx.x, lane = t & 63, w = t >> 6;
    int v = hist[b * G1 + t];
    int incl = v;
#pragma unroll
    for (int off = 1; off < 64; off <<= 1) {
        int tt = __shfl_up(incl, off);
        if (lane >= off) incl += tt;
    }
    if (lane == 63) wsum[w] = incl;
    __syncthreads();
    int p = 0;
    for (int j = 0; j < w; ++j) p += wsum[j];
    hist[b * G1 + t] = p + incl - v;          // bucket-local exclusive
    if (t == G1 - 1) bcount[b] = p + incl;    // bucket total
}

// Counting-sort scatter. Each block redundantly scans bcount -> bucket starts
// (3KB L2-hot read), so no separate scano kernel. Block 0 persists bstart.
__global__ __launch_bounds__(512) void k_sort(const void* __restrict__ ei,
                                              const int* __restrict__ hist,
                                              const int* __restrict__ bcount,
                                              int* __restrict__ bstart,
                                              unsigned* __restrict__ recs, int E, int NBv) {
    __shared__ int bst[NBMAX];
    __shared__ int cur[NBMAX];
    __shared__ int wsum[8];
    __shared__ int anynz;
    int is32 = detect_is32((const int*)ei, E, &anynz);
    int t = threadIdx.x, lane = t & 63, w = t >> 6;
    // exclusive prefix over NBv bucket totals (pairs per thread, 1024 slots)
    int i0p = 2 * t, i1p = 2 * t + 1;
    int v0 = (i0p < NBv) ? bcount[i0p] : 0;
    int v1 = (i1p < NBv) ? bcount[i1p] : 0;
    int s = v0 + v1;
    int incl = s;
#pragma unroll
    for (int off = 1; off < 64; off <<= 1) {
        int tt = __shfl_up(incl, off);
        if (lane >= off) incl += tt;
    }
    if (lane == 63) wsum[w] = incl;
    __syncthreads();
    int p = 0;
    for (int j = 0; j < w; ++j) p += wsum[j];
    int excl = p + incl - s;
    bst[i0p] = excl;
    bst[i1p] = excl + v0;
    __syncthreads();
    for (int b = t; b < NBv; b += 512)
        cur[b] = bst[b] + hist[b * G1 + blockIdx.x];
    if (blockIdx.x == 0)
        for (int b = t; b < NBv; b += 512) bstart[b] = bst[b];
    __syncthreads();
    int EB = (E + G1 - 1) / G1;
    int e0 = blockIdx.x * EB;
    int e1 = min(E, e0 + EB);
    for (int i = e0 + t; i < e1; i += 512) {
        int sv = load_idx(ei, i, is32);
        int d = load_idx(ei, (long long)E + i, is32);
        int b = d >> RBS;
        int pos = atomicAdd(&cur[b], 1);      // LDS cursor only
        recs[pos] = ((unsigned)(d & (RB - 1)) << 17) | (unsigned)sv;
    }
}

// Per-bucket in-degree via LDS histogram -> dis = rsqrt(deg+1)
__global__ __launch_bounds__(256) void k_deg(const unsigned* __restrict__ recs,
                                             const int* __restrict__ bstart, const int* __restrict__ bcount,
                                             float* __restrict__ dis, int n) {
    __shared__ int cnt[RB];
    for (int i = threadIdx.x; i < RB; i += 256) cnt[i] = 0;
    __syncthreads();
    int b = blockIdx.x;
    int s0 = bstart[b], s1 = s0 + bcount[b];
    for (int i = s0 + threadIdx.x; i < s1; i += 256)
        atomicAdd(&cnt[recs[i] >> 17], 1);
    __syncthreads();
    int rbase = b << RBS;
    for (int r = threadIdx.x; r < RB; r += 256) {
        int row = rbase + r;
        if (row < n) dis[row] = rsqrtf((float)(cnt[r] + 1));
    }
}

// Grid-stride, one wave per row, W slice in registers: y = dis[row]*(x@W)
__global__ __launch_bounds__(256) void k_gemm(const float* __restrict__ x, const float* __restrict__ W,
                                              const float* __restrict__ dis, float4* __restrict__ y4,
                                              int n, int nwaves) {
    int lane = threadIdx.x & 63;
    float4 w4[6];
    const float4* wp = (const float4*)W;
#pragma unroll
    for (int j = 0; j < 6; ++j) w4[j] = wp[lane * 6 + j];
    const float* wf = (const float*)w4;

    int wid = blockIdx.x * 4 + (threadIdx.x >> 6);
    for (int row = wid; row < n; row += nwaves) {
        const float4* xp = (const float4*)(x + (size_t)row * NF) + lane * 2;
        float4 a = xp[0], b = xp[1];
        float xv[8] = {a.x, a.y, a.z, a.w, b.x, b.y, b.z, b.w};
        float s0 = 0.f, s1 = 0.f, s2 = 0.f;
#pragma unroll
        for (int j = 0; j < 8; ++j) {
            s0 += xv[j] * wf[j * 3 + 0];
            s1 += xv[j] * wf[j * 3 + 1];
            s2 += xv[j] * wf[j * 3 + 2];
        }
#pragma unroll
        for (int off = 32; off; off >>= 1) {
            s0 += __shfl_down(s0, off);
            s1 += __shfl_down(s1, off);
            s2 += __shfl_down(s2, off);
        }
        if (lane == 0) {
            float di = dis[row];
            y4[row] = make_float4(s0 * di, s1 * di, s2 * di, 0.f);
        }
    }
}

// One block per bucket: aggregate u[d] = sum y[src] in LDS, then finalize
// h = relu(dis*(u + y_self) + bg), z = h@Wo + bo.
__global__ __launch_bounds__(256) void k_aggfinal(const unsigned* __restrict__ recs,
                                                  const int* __restrict__ bstart, const int* __restrict__ bcount,
                                                  const float4* __restrict__ y4, const float* __restrict__ dis,
                                                  const float* __restrict__ bg,
                                                  const float* __restrict__ Wo, const float* __restrict__ bo,
                                                  float* __restrict__ outH, float* __restrict__ outZ, int n) {
    __shared__ float u[RB * 3];
    for (int i = threadIdx.x; i < RB * 3; i += 256) u[i] = 0.f;
    __syncthreads();
    int b = blockIdx.x;
    int i0 = bstart[b], i1 = i0 + bcount[b];
    for (int i = i0 + threadIdx.x; i < i1; i += 256) {
        unsigned rec = recs[i];
        int src = rec & 0x1FFFF;
        int r = rec >> 17;
        float4 v = y4[src];
        atomicAdd(&u[r * 3 + 0], v.x);
        atomicAdd(&u[r * 3 + 1], v.y);
        atomicAdd(&u[r * 3 + 2], v.z);
    }
    __syncthreads();
    float b0 = bg[0], b1 = bg[1], b2 = bg[2];
    int rbase = b << RBS;
    for (int r = threadIdx.x; r < RB; r += 256) {
        int row = rbase + r;
        if (row >= n) break;
        float4 yv = y4[row];
        float di = dis[row];
        float h0 = fmaxf(di * (u[r * 3 + 0] + yv.x) + b0, 0.f);
        float h1 = fmaxf(di * (u[r * 3 + 1] + yv.y) + b1, 0.f);
        float h2 = fmaxf(di * (u[r * 3 + 2] + yv.z) + b2, 0.f);
        outH[row * 3 + 0] = h0; outH[row * 3 + 1] = h1; outH[row * 3 + 2] = h2;
#pragma unroll
        for (int c = 0; c < NC; ++c)
            outZ[row * NC + c] = h0 * Wo[c] + h1 * Wo[NC + c] + h2 * Wo[2 * NC + c] + bo[c];
    }
}

// ---------- atomic fallback (round-1 structure) ----------

__global__ void k_detect_fb(const int* ei, int* flag, int E) {
    __shared__ int anynz;
    if (threadIdx.x == 0) anynz = 0;
    __syncthreads();
    int lim = E < 2048 ? E : 2048;
    int nz = 0;
    for (int i = threadIdx.x; i < lim; i += blockDim.x) nz |= ei[2 * i + 1];
    if (nz) atomicOr(&anynz, 1);
    __syncthreads();
    if (threadIdx.x == 0) *flag = anynz;
}
__global__ void k_init_fb(float* deg, int n) {
    int i = blockIdx.x * blockDim.x + threadIdx.x;
    if (i < n) deg[i] = 1.0f;
}
__global__ void k_degc_fb(const void* ei, const int* flag, float* deg, int E, int n) {
    int i = blockIdx.x * blockDim.x + threadIdx.x;
    if (i >= E) return;
    int d = load_idx(ei, (long long)E + i, *flag);
    if ((unsigned)d < (unsigned)n) atomicAdd(&deg[d], 1.0f);
}
__global__ __launch_bounds__(256) void k_gemm_fb(const float* x, const float* W, float* degdis,
                                                 float* xw, float* agg, int n) {
    __shared__ float wl[NF * NH];
    for (int j = threadIdx.x; j < NF * NH; j += 256) wl[j] = W[j];
    __syncthreads();
    int row = blockIdx.x * 4 + (threadIdx.x >> 6);
    if (row >= n) return;
    int lane = threadIdx.x & 63;
    const float4* xp = (const float4*)(x + (size_t)row * NF + lane * 8);
    float4 a = xp[0], b = xp[1];
    float xv[8] = {a.x, a.y, a.z, a.w, b.x, b.y, b.z, b.w};
    float s0 = 0.f, s1 = 0.f, s2 = 0.f;
    int f0 = lane * 8;
#pragma unroll
    for (int j = 0; j < 8; ++j) {
        float v = xv[j];
        const float* wp = &wl[(f0 + j) * NH];
        s0 += v * wp[0]; s1 += v * wp[1]; s2 += v * wp[2];
    }
#pragma unroll
    for (int off = 32; off; off >>= 1) {
        s0 += __shfl_down(s0, off); s1 += __shfl_down(s1, off); s2 += __shfl_down(s2, off);
    }
    if (lane == 0) {
        float d = degdis[row];
        float di = d > 0.f ? rsqrtf(d) : 0.f;
        degdis[row] = di;
        xw[row * 3 + 0] = s0; xw[row * 3 + 1] = s1; xw[row * 3 + 2] = s2;
        float n2 = di * di;
        agg[row * 3 + 0] = s0 * n2; agg[row * 3 + 1] = s1 * n2; agg[row * 3 + 2] = s2 * n2;
    }
}
__global__ void k_scat_fb(const void* ei, const int* flag, const float* dis, const float* xw,
                          float* agg, int E, int n) {
    int i = blockIdx.x * blockDim.x + threadIdx.x;
    if (i >= E) return;
    int is32 = *flag;
    int s = load_idx(ei, i, is32);
    int d = load_idx(ei, (long long)E + i, is32);
    if ((unsigned)s >= (unsigned)n || (unsigned)d >= (unsigned)n) return;
    float w = dis[s] * dis[d];
    atomicAdd(&agg[d * 3 + 0], xw[s * 3 + 0] * w);
    atomicAdd(&agg[d * 3 + 1], xw[s * 3 + 1] * w);
    atomicAdd(&agg[d * 3 + 2], xw[s * 3 + 2] * w);
}
__global__ void k_final_fb(const float* agg, const float* bg, const float* Wo, const float* bo,
                           float* outH, float* outZ, int n) {
    int i = blockIdx.x * blockDim.x + threadIdx.x;
    if (i >= n) return;
    float h0 = fmaxf(agg[i * 3 + 0] + bg[0], 0.f);
    float h1 = fmaxf(agg[i * 3 + 1] + bg[1], 0.f);
    float h2 = fmaxf(agg[i * 3 + 2] + bg[2], 0.f);
    outH[i * 3 + 0] = h0; outH[i * 3 + 1] = h1; outH[i * 3 + 2] = h2;
#pragma unroll
    for (int c = 0; c < NC; ++c)
        outZ[i * NC + c] = h0 * Wo[c] + h1 * Wo[NC + c] + h2 * Wo[2 * NC + c] + bo[c];
}

// ---------- launch ----------

extern "C" void kernel_launch(void* const* d_in, const int* in_sizes, int n_in,
                              void* d_out, int out_size, void* d_ws, size_t ws_size,
                              hipStream_t stream) {
    const float* x  = (const float*)d_in[0];
    const void*  ei = d_in[1];
    const float* Wg = (const float*)d_in[2];
    const float* bg = (const float*)d_in[3];
    const float* Wo = (const float*)d_in[4];
    const float* bo = (const float*)d_in[5];

    const int N = in_sizes[0] / NF;
    const int E = in_sizes[1] / 2;
    const int NBv = (N + RB - 1) >> RBS;

    float* outH = (float*)d_out;
    float* outZ = outH + (size_t)3 * N;

    int*   wsI = (int*)d_ws;
    float* wsF = (float*)d_ws;

    size_t off = 64;
    int* hist   = wsI + off; off += (size_t)NBMAX * G1;
    int* bstart = wsI + off; off += NBMAX;
    int* bcount = wsI + off; off += NBMAX;
    float* dis  = wsF + off; off += N;
    off = (off + 3) & ~(size_t)3;
    float* y4   = wsF + off; off += (size_t)4 * N;
    unsigned* recs = (unsigned*)(wsI + off); off += E;

    bool fast = (off * 4 <= ws_size) && (N <= 131072) && (NBv <= NBMAX);

    if (fast) {
        k_hist<<<G1, dim3(512), 0, stream>>>(ei, hist, E, NBv);
        k_scanb<<<NBv, dim3(G1), 0, stream>>>(hist, bcount);
        k_sort<<<G1, dim3(512), 0, stream>>>(ei, hist, bcount, bstart, recs, E, NBv);
        k_deg<<<NBv, dim3(256), 0, stream>>>(recs, bstart, bcount, dis, N);
        k_gemm<<<2048, dim3(256), 0, stream>>>(x, Wg, dis, (float4*)y4, N, 2048 * 4);
        k_aggfinal<<<NBv, dim3(256), 0, stream>>>(recs, bstart, bcount, (const float4*)y4, dis,
                                                  bg, Wo, bo, outH, outZ, N);
    } else {
        int* flag  = wsI;
        float* deg = wsF + 64;
        float* xw  = deg + N;
        float* agg = xw + (size_t)3 * N;
        int gN = (N + 255) / 256, gE = (E + 255) / 256;
        dim3 blk(256);
        k_detect_fb<<<1, blk, 0, stream>>>((const int*)ei, flag, E);
        k_init_fb<<<gN, blk, 0, stream>>>(deg, N);
        k_degc_fb<<<gE, blk, 0, stream>>>(ei, flag, deg, E, N);
        k_gemm_fb<<<(N + 3) / 4, blk, 0, stream>>>(x, Wg, deg, xw, agg, N);
        k_scat_fb<<<gE, blk, 0, stream>>>(ei, flag, deg, xw, agg, E, N);
        k_final_fb<<<gN, blk, 0, stream>>>(agg, bg, Wo, bo, outH, outZ, N);
    }
}

// Round 8
// 150.865 us; speedup vs baseline: 3.0217x; 1.1049x over previous
//
#include <hip/hip_runtime.h>

#define NF 512
#define NH 3
#define NC 7
#define RB 128         // rows per dst bucket (power of two)
#define RBS 7          // log2(RB)
#define G1 256         // edge slice blocks for hist/sort
#define NBMAX 1024     // max buckets (N <= 131072)

// ---------- common ----------

__device__ __forceinline__ int load_idx(const void* base, long long i, int is32) {
    return is32 ? ((const int*)base)[i] : (int)((const long long*)base)[i];
}

// Per-block inline dtype detection: int64 layout has all-odd-words zero over the
// first 2048 pairs; int32 layout has (almost surely) nonzero there.
__device__ __forceinline__ int detect_is32(const int* __restrict__ ei, int E, int* anynz) {
    if (threadIdx.x == 0) *anynz = 0;
    __syncthreads();
    int lim = E < 2048 ? E : 2048;
    int nz = 0;
    for (int i = threadIdx.x; i < lim; i += blockDim.x) nz |= ei[2 * i + 1];
    if (nz) atomicOr(anynz, 1);
    __syncthreads();
    return *anynz;
}

// GEMM role: grid-stride waves over rows [row0,row1), W slice in registers.
// Writes y4[row].xyz = x[row]@W (UNSCALED). Never touches .w (deg owns it).
__device__ __forceinline__ void gemm_rows(const float* __restrict__ x, const float* __restrict__ W,
                                          float* __restrict__ y4f, int row0, int row1,
                                          int wid, int nwaves) {
    int lane = threadIdx.x & 63;
    float4 w4[6];
    const float4* wp = (const float4*)W;
#pragma unroll
    for (int j = 0; j < 6; ++j) w4[j] = wp[lane * 6 + j];
    const float* wf = (const float*)w4;
    for (int row = row0 + wid; row < row1; row += nwaves) {
        const float4* xp = (const float4*)(x + (size_t)row * NF) + lane * 2;
        float4 a = xp[0], b = xp[1];
        float xv[8] = {a.x, a.y, a.z, a.w, b.x, b.y, b.z, b.w};
        float s0 = 0.f, s1 = 0.f, s2 = 0.f;
#pragma unroll
        for (int j = 0; j < 8; ++j) {
            s0 += xv[j] * wf[j * 3 + 0];
            s1 += xv[j] * wf[j * 3 + 1];
            s2 += xv[j] * wf[j * 3 + 2];
        }
#pragma unroll
        for (int off = 32; off; off >>= 1) {
            s0 += __shfl_down(s0, off);
            s1 += __shfl_down(s1, off);
            s2 += __shfl_down(s2, off);
        }
        if (lane == 0) {
            *(float2*)(y4f + 4 * (size_t)row) = make_float2(s0, s1);
            y4f[4 * (size_t)row + 2] = s2;
        }
    }
}

// ---------- fast path (5 kernels, gemm co-scheduled with CSR phases) ----------

// K1: blocks [0,G1) histogram their edge slice; blocks [G1,..) run gemm rows [0,row1)
__global__ __launch_bounds__(256) void k_histgemm(const void* __restrict__ ei, int* __restrict__ hist,
                                                  int E, int NBv,
                                                  const float* __restrict__ x, const float* __restrict__ W,
                                                  float* __restrict__ y4f, int row1) {
    __shared__ int cnt[NBMAX];
    __shared__ int anynz;
    if (blockIdx.x < G1) {
        int is32 = detect_is32((const int*)ei, E, &anynz);
        for (int i = threadIdx.x; i < NBv; i += 256) cnt[i] = 0;
        __syncthreads();
        int EB = (E + G1 - 1) / G1;
        int e0 = blockIdx.x * EB;
        int e1 = min(E, e0 + EB);
        for (int i = e0 + threadIdx.x; i < e1; i += 256) {
            int d = load_idx(ei, (long long)E + i, is32);
            atomicAdd(&cnt[d >> RBS], 1);
        }
        __syncthreads();
        for (int b = threadIdx.x; b < NBv; b += 256)
            hist[b * G1 + blockIdx.x] = cnt[b];
    } else {
        int gb = gridDim.x - G1;
        gemm_rows(x, W, y4f, 0, row1, (blockIdx.x - G1) * 4 + (threadIdx.x >> 6), gb * 4);
    }
}

// K2: blocks [0,NBv) per-bucket exclusive scan of G1 counts; rest gemm [row1,row2)
__global__ __launch_bounds__(256) void k_scangemm(int* __restrict__ hist, int* __restrict__ bcount,
                                                  int NBv,
                                                  const float* __restrict__ x, const float* __restrict__ W,
                                                  float* __restrict__ y4f, int row1, int row2) {
    __shared__ int wsum[4];
    if (blockIdx.x < (unsigned)NBv) {
        int b = blockIdx.x;
        int t = threadIdx.x, lane = t & 63, w = t >> 6;
        int v = hist[b * G1 + t];
        int incl = v;
#pragma unroll
        for (int off = 1; off < 64; off <<= 1) {
            int tt = __shfl_up(incl, off);
            if (lane >= off) incl += tt;
        }
        if (lane == 63) wsum[w] = incl;
        __syncthreads();
        int p = 0;
        for (int j = 0; j < w; ++j) p += wsum[j];
        hist[b * G1 + t] = p + incl - v;          // bucket-local exclusive
        if (t == 255) bcount[b] = p + incl;       // bucket total
    } else {
        int gb = gridDim.x - NBv;
        gemm_rows(x, W, y4f, row1, row2, (blockIdx.x - NBv) * 4 + (threadIdx.x >> 6), gb * 4);
    }
}

// K3: blocks [0,G1) counting-sort scatter (redundant bstart scan from bcount);
//     rest gemm rows [row2,row3). Block 0 persists bstart.
__global__ __launch_bounds__(256) void k_sortgemm(const void* __restrict__ ei,
                                                  const int* __restrict__ hist,
                                                  const int* __restrict__ bcount,
                                                  int* __restrict__ bstart,
                                                  unsigned* __restrict__ recs, int E, int NBv,
                                                  const float* __restrict__ x, const float* __restrict__ W,
                                                  float* __restrict__ y4f, int row2, int row3) {
    __shared__ int bst[NBMAX];
    __shared__ int cur[NBMAX];
    __shared__ int wsum[4];
    __shared__ int anynz;
    if (blockIdx.x < G1) {
        int is32 = detect_is32((const int*)ei, E, &anynz);
        int t = threadIdx.x, lane = t & 63, w = t >> 6;
        int b4 = t * 4;
        int v[4];
        int s = 0;
#pragma unroll
        for (int j = 0; j < 4; ++j) { v[j] = (b4 + j < NBv) ? bcount[b4 + j] : 0; s += v[j]; }
        int incl = s;
#pragma unroll
        for (int off = 1; off < 64; off <<= 1) {
            int tt = __shfl_up(incl, off);
            if (lane >= off) incl += tt;
        }
        if (lane == 63) wsum[w] = incl;
        __syncthreads();
        int p = 0;
        for (int j = 0; j < w; ++j) p += wsum[j];
        int run = p + incl - s;
#pragma unroll
        for (int j = 0; j < 4; ++j) {
            if (b4 + j < NBMAX) bst[b4 + j] = run;
            run += v[j];
        }
        __syncthreads();
        for (int b = t; b < NBv; b += 256)
            cur[b] = bst[b] + hist[b * G1 + blockIdx.x];
        if (blockIdx.x == 0)
            for (int b = t; b < NBv; b += 256) bstart[b] = bst[b];
        __syncthreads();
        int EB = (E + G1 - 1) / G1;
        int e0 = blockIdx.x * EB;
        int e1 = min(E, e0 + EB);
        for (int i = e0 + t; i < e1; i += 256) {
            int sv = load_idx(ei, i, is32);
            int d = load_idx(ei, (long long)E + i, is32);
            int b = d >> RBS;
            int pos = atomicAdd(&cur[b], 1);      // LDS cursor only
            recs[pos] = ((unsigned)(d & (RB - 1)) << 17) | (unsigned)sv;
        }
    } else {
        int gb = gridDim.x - G1;
        gemm_rows(x, W, y4f, row2, row3, (blockIdx.x - G1) * 4 + (threadIdx.x >> 6), gb * 4);
    }
}

// K4: blocks [0,NBv) per-bucket in-degree -> y4[row].w = rsqrt(deg+1);
//     rest gemm rows [row3,N). Disjoint bytes of y4, no race.
__global__ __launch_bounds__(256) void k_deggemm(const unsigned* __restrict__ recs,
                                                 const int* __restrict__ bstart, const int* __restrict__ bcount,
                                                 float* __restrict__ y4f, int n, int NBv,
                                                 const float* __restrict__ x, const float* __restrict__ W,
                                                 int row3) {
    __shared__ int cnt[RB];
    if (blockIdx.x < (unsigned)NBv) {
        for (int i = threadIdx.x; i < RB; i += 256) cnt[i] = 0;
        __syncthreads();
        int b = blockIdx.x;
        int s0 = bstart[b], s1 = s0 + bcount[b];
        for (int i = s0 + threadIdx.x; i < s1; i += 256)
            atomicAdd(&cnt[recs[i] >> 17], 1);
        __syncthreads();
        int rbase = b << RBS;
        for (int r = threadIdx.x; r < RB; r += 256) {
            int row = rbase + r;
            if (row < n) y4f[4 * (size_t)row + 3] = rsqrtf((float)(cnt[r] + 1));
        }
    } else {
        int gb = gridDim.x - NBv;
        gemm_rows(x, W, y4f, row3, n, (blockIdx.x - NBv) * 4 + (threadIdx.x >> 6), gb * 4);
    }
}

// K5: one block per bucket: u[d] = sum dis[s]*xw[s] (dis rides in y4.w, ONE 16B
// gather per record, 4x unrolled for MLP), then finalize + out GEMM.
__global__ __launch_bounds__(256) void k_aggfinal(const unsigned* __restrict__ recs,
                                                  const int* __restrict__ bstart, const int* __restrict__ bcount,
                                                  const float4* __restrict__ y4, const float* __restrict__ bg,
                                                  const float* __restrict__ Wo, const float* __restrict__ bo,
                                                  float* __restrict__ outH, float* __restrict__ outZ, int n) {
    __shared__ float u[RB * 3];
    for (int i = threadIdx.x; i < RB * 3; i += 256) u[i] = 0.f;
    __syncthreads();
    int b = blockIdx.x;
    int i0 = bstart[b], i1 = i0 + bcount[b];
    int t = threadIdx.x;
    int i = i0 + t;
    for (; i + 768 < i1; i += 1024) {
        unsigned r0 = recs[i], r1 = recs[i + 256], r2 = recs[i + 512], r3 = recs[i + 768];
        float4 v0 = y4[r0 & 0x1FFFF], v1 = y4[r1 & 0x1FFFF],
               v2 = y4[r2 & 0x1FFFF], v3 = y4[r3 & 0x1FFFF];
        atomicAdd(&u[(r0 >> 17) * 3 + 0], v0.w * v0.x);
        atomicAdd(&u[(r0 >> 17) * 3 + 1], v0.w * v0.y);
        atomicAdd(&u[(r0 >> 17) * 3 + 2], v0.w * v0.z);
        atomicAdd(&u[(r1 >> 17) * 3 + 0], v1.w * v1.x);
        atomicAdd(&u[(r1 >> 17) * 3 + 1], v1.w * v1.y);
        atomicAdd(&u[(r1 >> 17) * 3 + 2], v1.w * v1.z);
        atomicAdd(&u[(r2 >> 17) * 3 + 0], v2.w * v2.x);
        atomicAdd(&u[(r2 >> 17) * 3 + 1], v2.w * v2.y);
        atomicAdd(&u[(r2 >> 17) * 3 + 2], v2.w * v2.z);
        atomicAdd(&u[(r3 >> 17) * 3 + 0], v3.w * v3.x);
        atomicAdd(&u[(r3 >> 17) * 3 + 1], v3.w * v3.y);
        atomicAdd(&u[(r3 >> 17) * 3 + 2], v3.w * v3.z);
    }
    for (; i < i1; i += 256) {
        unsigned rec = recs[i];
        float4 v = y4[rec & 0x1FFFF];
        int r = rec >> 17;
        atomicAdd(&u[r * 3 + 0], v.w * v.x);
        atomicAdd(&u[r * 3 + 1], v.w * v.y);
        atomicAdd(&u[r * 3 + 2], v.w * v.z);
    }
    __syncthreads();
    float b0 = bg[0], b1 = bg[1], b2 = bg[2];
    int rbase = b << RBS;
    for (int r = t; r < RB; r += 256) {
        int row = rbase + r;
        if (row >= n) break;
        float4 yv = y4[row];
        float di = yv.w;
        float h0 = fmaxf(di * (u[r * 3 + 0] + di * yv.x) + b0, 0.f);
        float h1 = fmaxf(di * (u[r * 3 + 1] + di * yv.y) + b1, 0.f);
        float h2 = fmaxf(di * (u[r * 3 + 2] + di * yv.z) + b2, 0.f);
        outH[row * 3 + 0] = h0; outH[row * 3 + 1] = h1; outH[row * 3 + 2] = h2;
#pragma unroll
        for (int c = 0; c < NC; ++c)
            outZ[row * NC + c] = h0 * Wo[c] + h1 * Wo[NC + c] + h2 * Wo[2 * NC + c] + bo[c];
    }
}

// ---------- atomic fallback (round-1 structure) ----------

__global__ void k_detect_fb(const int* ei, int* flag, int E) {
    __shared__ int anynz;
    if (threadIdx.x == 0) anynz = 0;
    __syncthreads();
    int lim = E < 2048 ? E : 2048;
    int nz = 0;
    for (int i = threadIdx.x; i < lim; i += blockDim.x) nz |= ei[2 * i + 1];
    if (nz) atomicOr(&anynz, 1);
    __syncthreads();
    if (threadIdx.x == 0) *flag = anynz;
}
__global__ void k_init_fb(float* deg, int n) {
    int i = blockIdx.x * blockDim.x + threadIdx.x;
    if (i < n) deg[i] = 1.0f;
}
__global__ void k_degc_fb(const void* ei, const int* flag, float* deg, int E, int n) {
    int i = blockIdx.x * blockDim.x + threadIdx.x;
    if (i >= E) return;
    int d = load_idx(ei, (long long)E + i, *flag);
    if ((unsigned)d < (unsigned)n) atomicAdd(&deg[d], 1.0f);
}
__global__ __launch_bounds__(256) void k_gemm_fb(const float* x, const float* W, float* degdis,
                                                 float* xw, float* agg, int n) {
    __shared__ float wl[NF * NH];
    for (int j = threadIdx.x; j < NF * NH; j += 256) wl[j] = W[j];
    __syncthreads();
    int row = blockIdx.x * 4 + (threadIdx.x >> 6);
    if (row >= n) return;
    int lane = threadIdx.x & 63;
    const float4* xp = (const float4*)(x + (size_t)row * NF + lane * 8);
    float4 a = xp[0], b = xp[1];
    float xv[8] = {a.x, a.y, a.z, a.w, b.x, b.y, b.z, b.w};
    float s0 = 0.f, s1 = 0.f, s2 = 0.f;
    int f0 = lane * 8;
#pragma unroll
    for (int j = 0; j < 8; ++j) {
        float v = xv[j];
        const float* wp = &wl[(f0 + j) * NH];
        s0 += v * wp[0]; s1 += v * wp[1]; s2 += v * wp[2];
    }
#pragma unroll
    for (int off = 32; off; off >>= 1) {
        s0 += __shfl_down(s0, off); s1 += __shfl_down(s1, off); s2 += __shfl_down(s2, off);
    }
    if (lane == 0) {
        float d = degdis[row];
        float di = d > 0.f ? rsqrtf(d) : 0.f;
        degdis[row] = di;
        xw[row * 3 + 0] = s0; xw[row * 3 + 1] = s1; xw[row * 3 + 2] = s2;
        float n2 = di * di;
        agg[row * 3 + 0] = s0 * n2; agg[row * 3 + 1] = s1 * n2; agg[row * 3 + 2] = s2 * n2;
    }
}
__global__ void k_scat_fb(const void* ei, const int* flag, const float* dis, const float* xw,
                          float* agg, int E, int n) {
    int i = blockIdx.x * blockDim.x + threadIdx.x;
    if (i >= E) return;
    int is32 = *flag;
    int s = load_idx(ei, i, is32);
    int d = load_idx(ei, (long long)E + i, is32);
    if ((unsigned)s >= (unsigned)n || (unsigned)d >= (unsigned)n) return;
    float w = dis[s] * dis[d];
    atomicAdd(&agg[d * 3 + 0], xw[s * 3 + 0] * w);
    atomicAdd(&agg[d * 3 + 1], xw[s * 3 + 1] * w);
    atomicAdd(&agg[d * 3 + 2], xw[s * 3 + 2] * w);
}
__global__ void k_final_fb(const float* agg, const float* bg, const float* Wo, const float* bo,
                           float* outH, float* outZ, int n) {
    int i = blockIdx.x * blockDim.x + threadIdx.x;
    if (i >= n) return;
    float h0 = fmaxf(agg[i * 3 + 0] + bg[0], 0.f);
    float h1 = fmaxf(agg[i * 3 + 1] + bg[1], 0.f);
    float h2 = fmaxf(agg[i * 3 + 2] + bg[2], 0.f);
    outH[i * 3 + 0] = h0; outH[i * 3 + 1] = h1; outH[i * 3 + 2] = h2;
#pragma unroll
    for (int c = 0; c < NC; ++c)
        outZ[i * NC + c] = h0 * Wo[c] + h1 * Wo[NC + c] + h2 * Wo[2 * NC + c] + bo[c];
}

// ---------- launch ----------

extern "C" void kernel_launch(void* const* d_in, const int* in_sizes, int n_in,
                              void* d_out, int out_size, void* d_ws, size_t ws_size,
                              hipStream_t stream) {
    const float* x  = (const float*)d_in[0];
    const void*  ei = d_in[1];
    const float* Wg = (const float*)d_in[2];
    const float* bg = (const float*)d_in[3];
    const float* Wo = (const float*)d_in[4];
    const float* bo = (const float*)d_in[5];

    const int N = in_sizes[0] / NF;
    const int E = in_sizes[1] / 2;
    const int NBv = (N + RB - 1) >> RBS;

    float* outH = (float*)d_out;
    float* outZ = outH + (size_t)3 * N;

    int*   wsI = (int*)d_ws;
    float* wsF = (float*)d_ws;

    size_t off = 64;
    int* hist   = wsI + off; off += (size_t)NBMAX * G1;
    int* bstart = wsI + off; off += NBMAX;
    int* bcount = wsI + off; off += NBMAX;
    off = (off + 3) & ~(size_t)3;
    float* y4   = wsF + off; off += (size_t)4 * N;
    unsigned* recs = (unsigned*)(wsI + off); off += E;

    bool fast = (off * 4 <= ws_size) && (N <= 131072) && (NBv <= NBMAX);

    if (fast) {
        // gemm row fractions co-scheduled with each CSR phase
        int r1 = (int)((long long)N * 30 / 100);
        int r2 = (int)((long long)N * 36 / 100);
        int r3 = (int)((long long)N * 81 / 100);
        k_histgemm<<<G1 + 512, dim3(256), 0, stream>>>(ei, hist, E, NBv, x, Wg, y4, r1);
        k_scangemm<<<NBv + 128, dim3(256), 0, stream>>>(hist, bcount, NBv, x, Wg, y4, r1, r2);
        k_sortgemm<<<G1 + 896, dim3(256), 0, stream>>>(ei, hist, bcount, bstart, recs, E, NBv,
                                                       x, Wg, y4, r2, r3);
        k_deggemm<<<NBv + 512, dim3(256), 0, stream>>>(recs, bstart, bcount, y4, N, NBv, x, Wg, r3);
        k_aggfinal<<<NBv, dim3(256), 0, stream>>>(recs, bstart, bcount, (const float4*)y4,
                                                  bg, Wo, bo, outH, outZ, N);
    } else {
        int* flag  = wsI;
        float* deg = wsF + 64;
        float* xw  = deg + N;
        float* agg = xw + (size_t)3 * N;
        int gN = (N + 255) / 256, gE = (E + 255) / 256;
        dim3 blk(256);
        k_detect_fb<<<1, blk, 0, stream>>>((const int*)ei, flag, E);
        k_init_fb<<<gN, blk, 0, stream>>>(deg, N);
        k_degc_fb<<<gE, blk, 0, stream>>>(ei, flag, deg, E, N);
        k_gemm_fb<<<(N + 3) / 4, blk, 0, stream>>>(x, Wg, deg, xw, agg, N);
        k_scat_fb<<<gE, blk, 0, stream>>>(ei, flag, deg, xw, agg, E, N);
        k_final_fb<<<gN, blk, 0, stream>>>(agg, bg, Wo, bo, outH, outZ, N);
    }
}